// Round 1
// baseline (285.506 us; speedup 1.0000x reference)
//
#include <hip/hip_runtime.h>
#include <stdint.h>

typedef unsigned short u16;
typedef unsigned int   u32;

#define NTOK   32768      // B*P
#define GD     768
#define GH     256
#define GH2    128
#define GE     64

typedef __bf16 bf16x8 __attribute__((ext_vector_type(8)));
typedef float  f32x4  __attribute__((ext_vector_type(4)));
union Frag { uint4 u; bf16x8 b; };

__device__ __forceinline__ float bf2f(u16 h) {
  union { u32 u; float f; } v; v.u = ((u32)h) << 16; return v.f;
}
__device__ __forceinline__ u16 f2bf(float f) {
  union { float f; u32 u; } v; v.f = f;
  u32 r = (v.u + 0x7fffu + ((v.u >> 16) & 1u)) >> 16;
  return (u16)r;
}

__device__ __forceinline__ void async16(void* lds, const void* g) {
  __builtin_amdgcn_global_load_lds(
      (const __attribute__((address_space(1))) void*)g,
      (__attribute__((address_space(3))) void*)lds, 16, 0, 0);
}

__device__ __forceinline__ int getProp(const int* p32, int t, int is64) {
  return is64 ? p32[2 * t] : p32[t];
}

// ---------------- workspace layout (bytes) ----------------
static const size_t OFF_Y    = 0;            // bf16 NTOK*768*2 = 50331648
static const size_t OFF_W1T  = 50331648;     // bf16 64*256*768*2 = 25165824
static const size_t OFF_W2T  = 75497472;     // bf16 64*128*256*2 = 4194304
static const size_t OFF_TOK  = 79691776;     // int  NTOK*4
static const size_t OFF_META = 79822848;     // ints (~46 KB)
// meta ints: counts2d[8192]@0, offsets[65]@8192, tileHead[1024]@8320,
//   tileRow[1024]@9344, nTiles@10368, flag@10369, cursors_p[1024]@10432

// ---------------- K0: zero out + prop-dtype flag + per-block histogram -------
__global__ void setup_kernel(const int* __restrict__ prop, const float* __restrict__ mask,
                             u32* __restrict__ outz, int* __restrict__ counts2d,
                             int* __restrict__ cursors_p, int* __restrict__ flagp) {
  __shared__ int h[GE];
  __shared__ int vOr;
  const int b = blockIdx.x;                 // grid 128
  const int tid = threadIdx.x;
  outz[b * 512 + tid] = 0u;
  outz[b * 512 + 256 + tid] = 0u;
  if (b < 4) cursors_p[b * 256 + tid] = 0;
  if (tid < GE) h[tid] = 0;
  if (tid == 0) vOr = 0;
  __syncthreads();
  int v = prop[2 * tid + 1] | prop[2 * (tid + 256) + 1];
  if (v) atomicOr(&vOr, 1);
  __syncthreads();
  const int is64 = (vOr == 0) ? 1 : 0;
  if (b == 0 && tid == 0) *flagp = is64;
  const int t = b * 256 + tid;
  if (mask[t] > 0.f) atomicAdd(&h[getProp(prop, t, is64)], 1);
  __syncthreads();
  if (tid < GE) counts2d[b * GE + tid] = h[tid];
}

// ---------------- K1a: W1 fp32 [64][768][256] -> bf16 [64][256][768] ----------
__global__ void transpose_w1(const float* __restrict__ in, u16* __restrict__ out) {
  __shared__ u16 tl[64][260];               // [h][d], 33.3 KB
  const int bid = blockIdx.x;               // grid 64*3*4 = 768
  const int e  = bid / 12, r = bid % 12;
  const int d0 = (r / 4) * 256, h0 = (r % 4) * 64;
  const int tid = threadIdx.x;
  const size_t inMat = (size_t)e * GD * GH;
  const size_t outMat = (size_t)e * GH * GD;
  const int h_l = (tid & 15) * 4, d_l = tid >> 4;
#pragma unroll
  for (int dd = 0; dd < 16; ++dd) {
    const int d = d_l + dd * 16;
    float4 v = *(const float4*)(in + inMat + (size_t)(d0 + d) * GH + h0 + h_l);
    tl[h_l + 0][d] = f2bf(v.x);
    tl[h_l + 1][d] = f2bf(v.y);
    tl[h_l + 2][d] = f2bf(v.z);
    tl[h_l + 3][d] = f2bf(v.w);
  }
  __syncthreads();
  const int wv = tid >> 6, ln = tid & 63;
#pragma unroll
  for (int hh = 0; hh < 16; ++hh) {
    const int h = wv * 16 + hh;
    *(uint2*)(out + outMat + (size_t)(h0 + h) * GD + d0 + ln * 4) =
        *(const uint2*)&tl[h][ln * 4];
  }
}

// ---------------- K1b: generic fp32 [E][R][C] -> bf16 [E][C][R] (W2) ----------
__global__ void transpose_kernel(const float* __restrict__ in, u16* __restrict__ out,
                                 int R, int C, int tilesC) {
  __shared__ u16 tile[32][33];
  const int tilesPerMat = (R >> 5) * tilesC;
  const int e  = blockIdx.x / tilesPerMat;
  const int t  = blockIdx.x % tilesPerMat;
  const int tr = t / tilesC, tc = t % tilesC;
  const size_t mat = (size_t)e * R * C;
  const int tx = threadIdx.x & 31, ty = threadIdx.x >> 5;
  const int r0 = tr * 32, c0 = tc * 32;
#pragma unroll
  for (int i = 0; i < 32; i += 8)
    tile[ty + i][tx] = f2bf(in[mat + (size_t)(r0 + ty + i) * C + c0 + tx]);
  __syncthreads();
#pragma unroll
  for (int i = 0; i < 32; i += 8)
    out[mat + (size_t)(c0 + ty + i) * R + r0 + tx] = tile[tx][ty + i];
}

// ---------------- K2: LayerNorm -> y bf16 (pure stream) -----------------------
__global__ void ln_kernel(const float* __restrict__ hs, const float* __restrict__ g,
                          const float* __restrict__ bta, const int* __restrict__ prop,
                          u16* __restrict__ y, const int* __restrict__ flag) {
  const int wv = threadIdx.x >> 6, ln = threadIdx.x & 63;
  const int t = blockIdx.x * 4 + wv;          // grid 8192
  const float* x = hs + (size_t)t * GD;
  float v[12];
  float s = 0.f, sq = 0.f;
#pragma unroll
  for (int c = 0; c < 3; ++c) {
    float4 u = *(const float4*)(x + c * 256 + ln * 4);
    v[c*4+0] = u.x; v[c*4+1] = u.y; v[c*4+2] = u.z; v[c*4+3] = u.w;
    s  += u.x + u.y + u.z + u.w;
    sq += u.x*u.x + u.y*u.y + u.z*u.z + u.w*u.w;
  }
#pragma unroll
  for (int d = 1; d < 64; d <<= 1) { s += __shfl_xor(s, d); sq += __shfl_xor(sq, d); }
  const float mu = s * (1.f / 768.f);
  const float rstd = rsqrtf(sq * (1.f / 768.f) - mu * mu + 1e-5f);
  const int p = getProp(prop, t, *flag);
  const float* gp = g + (size_t)p * GD;
  const float* bp = bta + (size_t)p * GD;
  u16* yp = y + (size_t)t * GD;
#pragma unroll
  for (int c = 0; c < 3; ++c) {
    float4 ug = *(const float4*)(gp + c * 256 + ln * 4);
    float4 ub = *(const float4*)(bp + c * 256 + ln * 4);
    float y0 = (v[c*4+0] - mu) * rstd * ug.x + ub.x;
    float y1 = (v[c*4+1] - mu) * rstd * ug.y + ub.y;
    float y2 = (v[c*4+2] - mu) * rstd * ug.z + ub.z;
    float y3 = (v[c*4+3] - mu) * rstd * ug.w + ub.w;
    uint2 o;
    o.x = (u32)f2bf(y0) | ((u32)f2bf(y1) << 16);
    o.y = (u32)f2bf(y2) | ((u32)f2bf(y3) << 16);
    *(uint2*)(yp + c * 256 + ln * 4) = o;
  }
}

// ---------------- K3: reduce counts2d + scan + tile table (64-row tiles) ------
__global__ void scan_kernel(const int* __restrict__ counts2d, int* __restrict__ offsets,
                            int* __restrict__ tileHead, int* __restrict__ tileRow,
                            int* __restrict__ nTilesPtr) {
  const int e = threadIdx.x;  // 0..63
  int c = 0;
  for (int b = 0; b < 128; ++b) c += counts2d[b * GE + e];
  int inc = c;
#pragma unroll
  for (int d = 1; d < 64; d <<= 1) { int n = __shfl_up(inc, d); if (e >= d) inc += n; }
  const int off = inc - c;
  offsets[e] = off;
  if (e == 63) offsets[64] = inc;
  int ntile = (c + 63) >> 6;
  int inct = ntile;
#pragma unroll
  for (int d = 1; d < 64; d <<= 1) { int n = __shfl_up(inct, d); if (e >= d) inct += n; }
  const int tb = inct - ntile;
  for (int j = 0; j < ntile; ++j) { tileHead[tb + j] = e; tileRow[tb + j] = off + j * 64; }
  if (e == 63) *nTilesPtr = inct;
}

// ---------------- K4: two-phase block scatter ---------------------------------
__global__ void scatter_kernel(const int* __restrict__ prop, const float* __restrict__ mask,
                               const int* __restrict__ offsets, int* __restrict__ cursors_p,
                               int* __restrict__ tokenIds, const int* __restrict__ flag) {
  __shared__ int h[GE];
  __shared__ int basebin[GE];
  const int tid = threadIdx.x;
  const int t = blockIdx.x * 256 + tid;  // grid 128
  if (tid < GE) h[tid] = 0;
  __syncthreads();
  int p = -1, rank = 0;
  if (mask[t] > 0.f) {
    p = getProp(prop, t, *flag);
    rank = atomicAdd(&h[p], 1);
  }
  __syncthreads();
  if (tid < GE && h[tid] > 0) basebin[tid] = atomicAdd(&cursors_p[tid * 16], h[tid]);
  __syncthreads();
  if (p >= 0) tokenIds[offsets[p] + basebin[p] + rank] = t;
}

// ---------------- K5: grouped fused adapter GEMM -------------------------------
// 64-row x 256-col tiles, single GEMM1 pass, k-group-major LDS staging.
// LDS: union(stage 40KB, h 34KB) + sB2 16KB + misc ~3KB = ~59KB -> 2 blocks/CU.
__global__ __launch_bounds__(256, 2) void adapter_gemm(
    const u16* __restrict__ y, const u16* __restrict__ w1t, const u16* __restrict__ w2t,
    const float* __restrict__ b1, const float* __restrict__ b2,
    const float* __restrict__ w3, const float* __restrict__ b3,
    const float* __restrict__ base, const float* __restrict__ mask,
    const int* __restrict__ tokenIds, const int* __restrict__ offsets,
    const int* __restrict__ tileHead, const int* __restrict__ tileRow,
    const int* __restrict__ nTilesPtr, float* __restrict__ outp) {
  __shared__ union LU {
    struct { u16 A[2][2048]; u16 B[2][8192]; } s;   // staging: [kgrp4][row][8]
    u16 h[17408];                                   // h1 stride 264 / h2 stride 130
  } uni;
  __shared__ u16 sB2[2][4096];   // GEMM2 B staging [kgrp4][n128][8], dbuf
  __shared__ float sBias1[256];
  __shared__ float sBias2[128];
  __shared__ float sW3[2][128];
  __shared__ float sB3[2];
  __shared__ int   sTok[64];

  const int tid  = threadIdx.x;
  const int wv   = tid >> 6;
  const int ln   = tid & 63;
  const int l15  = tid & 15;
  const int quad = (tid & 63) >> 4;
  const f32x4 vzero = {0.f, 0.f, 0.f, 0.f};
  const int nt = *nTilesPtr;

  for (int tile = blockIdx.x; tile < nt; tile += gridDim.x) {
    __syncthreads();  // protect LDS/meta reuse across tiles
    const int e  = tileHead[tile];
    const int rs = tileRow[tile];
    const int nRows = min(64, offsets[e + 1] - rs);

    if (tid < 64) sTok[tid] = tokenIds[rs + min(tid, nRows - 1)];
    sBias1[tid] = b1[e * GH + tid];
    if (tid < 128) sBias2[tid] = b2[e * GH2 + tid];
    { const int k = tid >> 1, o = tid & 1; sW3[o][k] = w3[e * GH2 * 2 + k * 2 + o]; }
    if (tid < 2) sB3[tid] = b3[e * 2 + tid];
    __syncthreads();

    const u16* yrow = y + (size_t)sTok[ln] * GD;       // per-lane row pointer
    const u16* w1e = w1t + (size_t)e * GH * GD;
    const u16* w2e = w2t + (size_t)e * GH2 * GH;

    // ---- GEMM1: y[64x768] @ W1t -> h1[64x256]; 24 k-steps, BK=32 ----
    f32x4 acc1[4][4];
#pragma unroll
    for (int f = 0; f < 4; ++f)
#pragma unroll
      for (int g = 0; g < 4; ++g) acc1[f][g] = vzero;

    // prefetch kt=0: wave wv stages k-group wv (k = k0 + wv*8 .. +7)
    {
      async16(uni.s.A[0] + wv * 512, yrow + wv * 8);
#pragma unroll
      for (int j = 0; j < 4; ++j)
        async16(uni.s.B[0] + wv * 2048 + j * 512,
                w1e + (size_t)(j * 64 + ln) * GD + wv * 8);
    }

    for (int kt = 0; kt < 24; ++kt) {
      __syncthreads();   // drains kt's staging loads (issued one iter ago)
      if (kt + 1 < 24) {
        const int k0 = (kt + 1) * 32;
        const int par = (kt + 1) & 1;
        async16(uni.s.A[par] + wv * 512, yrow + k0 + wv * 8);
#pragma unroll
        for (int j = 0; j < 4; ++j)
          async16(uni.s.B[par] + wv * 2048 + j * 512,
                  w1e + (size_t)(j * 64 + ln) * GD + k0 + wv * 8);
      }
      const int par = kt & 1;
      Frag fa[4], fb[4];
#pragma unroll
      for (int f = 0; f < 4; ++f)
        fa[f].u = *(const uint4*)&uni.s.A[par][quad * 512 + (f * 16 + l15) * 8];
#pragma unroll
      for (int g = 0; g < 4; ++g)
        fb[g].u = *(const uint4*)&uni.s.B[par][quad * 2048 + (wv * 64 + g * 16 + l15) * 8];
#pragma unroll
      for (int f = 0; f < 4; ++f)
#pragma unroll
        for (int g = 0; g < 4; ++g)
          acc1[f][g] = __builtin_amdgcn_mfma_f32_16x16x32_bf16(fa[f].b, fb[g].b, acc1[f][g], 0, 0, 0);
    }
    __syncthreads();   // staging region fully read -> uni.h writable

    // prefetch GEMM2 B kt=0 (separate region; overlaps epilogue VALU)
#pragma unroll
    for (int j = 0; j < 2; ++j)
      async16(sB2[0] + wv * 1024 + j * 512,
              w2e + (size_t)(j * 64 + ln) * GH + wv * 8);

    // epilogue 1: +b1, relu -> uni.h (stride 264)
#pragma unroll
    for (int f = 0; f < 4; ++f)
#pragma unroll
      for (int g = 0; g < 4; ++g) {
        const int col = wv * 64 + g * 16 + l15;
        const float bias = sBias1[col];
#pragma unroll
        for (int r = 0; r < 4; ++r) {
          const int row = f * 16 + quad * 4 + r;
          uni.h[row * 264 + col] = f2bf(fmaxf(acc1[f][g][r] + bias, 0.f));
        }
      }

    // ---- GEMM2: h1[64x256] @ W2t -> 64x128; 8 k-steps ----
    f32x4 acc2[4][2];
#pragma unroll
    for (int f = 0; f < 4; ++f)
#pragma unroll
      for (int g = 0; g < 2; ++g) acc2[f][g] = vzero;

    for (int kt = 0; kt < 8; ++kt) {
      __syncthreads();   // drains kt's sB2 loads; also makes h1 visible (kt=0)
      if (kt + 1 < 8) {
        const int k0 = (kt + 1) * 32;
        const int par = (kt + 1) & 1;
#pragma unroll
        for (int j = 0; j < 2; ++j)
          async16(sB2[par] + wv * 1024 + j * 512,
                  w2e + (size_t)(j * 64 + ln) * GH + k0 + wv * 8);
      }
      const int par = kt & 1;
      Frag fa2[4], fb2[2];
#pragma unroll
      for (int f = 0; f < 4; ++f)
        fa2[f].u = *(const uint4*)&uni.h[(f * 16 + l15) * 264 + kt * 32 + quad * 8];
#pragma unroll
      for (int g = 0; g < 2; ++g)
        fb2[g].u = *(const uint4*)&sB2[par][quad * 1024 + (wv * 32 + g * 16 + l15) * 8];
#pragma unroll
      for (int f = 0; f < 4; ++f)
#pragma unroll
        for (int g = 0; g < 2; ++g)
          acc2[f][g] = __builtin_amdgcn_mfma_f32_16x16x32_bf16(fa2[f].b, fb2[g].b, acc2[f][g], 0, 0, 0);
    }
    __syncthreads();   // h1 reads done -> overwrite with h2

    // epilogue 2: +b2, relu -> uni.h as h2 (stride 130: bank-clean for GEMM3)
#pragma unroll
    for (int f = 0; f < 4; ++f)
#pragma unroll
      for (int g = 0; g < 2; ++g) {
        const int col = wv * 32 + g * 16 + l15;
        const float bias = sBias2[col];
#pragma unroll
        for (int r = 0; r < 4; ++r) {
          const int row = f * 16 + quad * 4 + r;
          uni.h[row * 130 + col] = f2bf(fmaxf(acc2[f][g][r] + bias, 0.f));
        }
      }
    __syncthreads();

    // ---------- GEMM3 + residual + mask + scatter-store (fp32) ----------
    const int m = tid >> 1, o = tid & 1;
    if (m < nRows) {
      float a = sB3[o];
      const u16* h2row = &uni.h[m * 130];
#pragma unroll 16
      for (int k = 0; k < 128; ++k) a += bf2f(h2row[k]) * sW3[o][k];
      const int t = sTok[m];
      const float mk = mask[t];
      const float bs = base[t * 2 + o];
      outp[t * 2 + o] = (0.7f * a + 0.3f * bs) * mk;
    }
  }
}

extern "C" void kernel_launch(void* const* d_in, const int* in_sizes, int n_in,
                              void* d_out, int out_size, void* d_ws, size_t ws_size,
                              hipStream_t stream) {
  const float* hs   = (const float*)d_in[0];
  const float* base = (const float*)d_in[1];
  const int*   prop = (const int*)d_in[2];
  const float* mask = (const float*)d_in[3];
  const float* lng  = (const float*)d_in[4];
  const float* lnb  = (const float*)d_in[5];
  const float* W1   = (const float*)d_in[6];
  const float* b1   = (const float*)d_in[7];
  const float* W2   = (const float*)d_in[8];
  const float* b2   = (const float*)d_in[9];
  const float* W3   = (const float*)d_in[10];
  const float* b3   = (const float*)d_in[11];

  char* ws = (char*)d_ws;
  u16* y    = (u16*)(ws + OFF_Y);
  u16* w1t  = (u16*)(ws + OFF_W1T);
  u16* w2t  = (u16*)(ws + OFF_W2T);
  int* tok  = (int*)(ws + OFF_TOK);
  int* meta = (int*)(ws + OFF_META);
  int* counts2d  = meta;           // 8192 ints
  int* offsets   = meta + 8192;    // 65 ints
  int* tileHead  = meta + 8320;    // 1024 ints
  int* tileRow   = meta + 9344;    // 1024 ints
  int* nTiles    = meta + 10368;
  int* propFlag  = meta + 10369;
  int* cursors_p = meta + 10432;   // 1024 ints (64 bins, 64B-padded)

  setup_kernel<<<128, 256, 0, stream>>>(prop, mask, (u32*)d_out, counts2d,
                                        cursors_p, propFlag);
  transpose_w1<<<768, 256, 0, stream>>>(W1, w1t);
  transpose_kernel<<<64 * 8 * 4, 256, 0, stream>>>(W2, w2t, GH, GH2, 4);
  ln_kernel<<<NTOK / 4, 256, 0, stream>>>(hs, lng, lnb, prop, y, propFlag);
  scan_kernel<<<1, 64, 0, stream>>>(counts2d, offsets, tileHead, tileRow, nTiles);
  scatter_kernel<<<NTOK / 256, 256, 0, stream>>>(prop, mask, offsets, cursors_p, tok, propFlag);
  adapter_gemm<<<640, 256, 0, stream>>>(y, w1t, w2t, b1, b2, W3, b3, base, mask,
                                        tok, offsets, tileHead, tileRow, nTiles,
                                        (float*)d_out);
}

// Round 2
// 276.642 us; speedup vs baseline: 1.0320x; 1.0320x over previous
//
#include <hip/hip_runtime.h>
#include <stdint.h>

typedef unsigned short u16;
typedef unsigned int   u32;

#define NTOK   32768      // B*P
#define GD     768
#define GH     256
#define GH2    128
#define GE     64

typedef __bf16 bf16x8 __attribute__((ext_vector_type(8)));
typedef float  f32x4  __attribute__((ext_vector_type(4)));
union Frag { uint4 u; bf16x8 b; };

__device__ __forceinline__ float bf2f(u16 h) {
  union { u32 u; float f; } v; v.u = ((u32)h) << 16; return v.f;
}
__device__ __forceinline__ u16 f2bf(float f) {
  union { float f; u32 u; } v; v.f = f;
  u32 r = (v.u + 0x7fffu + ((v.u >> 16) & 1u)) >> 16;
  return (u16)r;
}

__device__ __forceinline__ void async16(void* lds, const void* g) {
  __builtin_amdgcn_global_load_lds(
      (const __attribute__((address_space(1))) void*)g,
      (__attribute__((address_space(3))) void*)lds, 16, 0, 0);
}

__device__ __forceinline__ int getProp(const int* p32, int t, int is64) {
  return is64 ? p32[2 * t] : p32[t];
}

// ---------------- workspace layout (bytes) ----------------
// y workspace removed (LN fused into adapter_gemm)
static const size_t OFF_W1T  = 0;            // bf16 64*256*768*2 = 25165824
static const size_t OFF_W2T  = 25165824;     // bf16 64*128*256*2 = 4194304
static const size_t OFF_TOK  = 29360128;     // int  NTOK*4 = 131072
static const size_t OFF_META = 29491200;     // ints (~46 KB)
// meta ints: counts2d[8192]@0, offsets[65]@8192, tileHead[1024]@8320,
//   tileRow[1024]@9344, nTiles@10368, flag@10369, cursors_p[1024]@10432

// ---------------- K0: zero out + prop-dtype flag + per-block histogram -------
__global__ void setup_kernel(const int* __restrict__ prop, const float* __restrict__ mask,
                             u32* __restrict__ outz, int* __restrict__ counts2d,
                             int* __restrict__ cursors_p, int* __restrict__ flagp) {
  __shared__ int h[GE];
  __shared__ int vOr;
  const int b = blockIdx.x;                 // grid 128
  const int tid = threadIdx.x;
  outz[b * 512 + tid] = 0u;
  outz[b * 512 + 256 + tid] = 0u;
  if (b < 4) cursors_p[b * 256 + tid] = 0;
  if (tid < GE) h[tid] = 0;
  if (tid == 0) vOr = 0;
  __syncthreads();
  int v = prop[2 * tid + 1] | prop[2 * (tid + 256) + 1];
  if (v) atomicOr(&vOr, 1);
  __syncthreads();
  const int is64 = (vOr == 0) ? 1 : 0;
  if (b == 0 && tid == 0) *flagp = is64;
  const int t = b * 256 + tid;
  if (mask[t] > 0.f) atomicAdd(&h[getProp(prop, t, is64)], 1);
  __syncthreads();
  if (tid < GE) counts2d[b * GE + tid] = h[tid];
}

// ---------------- K1a: W1 fp32 [64][768][256] -> bf16 [64][256][768] ----------
__global__ void transpose_w1(const float* __restrict__ in, u16* __restrict__ out) {
  __shared__ u16 tl[64][260];               // [h][d], 33.3 KB
  const int bid = blockIdx.x;               // grid 64*3*4 = 768
  const int e  = bid / 12, r = bid % 12;
  const int d0 = (r / 4) * 256, h0 = (r % 4) * 64;
  const int tid = threadIdx.x;
  const size_t inMat = (size_t)e * GD * GH;
  const size_t outMat = (size_t)e * GH * GD;
  const int h_l = (tid & 15) * 4, d_l = tid >> 4;
#pragma unroll
  for (int dd = 0; dd < 16; ++dd) {
    const int d = d_l + dd * 16;
    float4 v = *(const float4*)(in + inMat + (size_t)(d0 + d) * GH + h0 + h_l);
    tl[h_l + 0][d] = f2bf(v.x);
    tl[h_l + 1][d] = f2bf(v.y);
    tl[h_l + 2][d] = f2bf(v.z);
    tl[h_l + 3][d] = f2bf(v.w);
  }
  __syncthreads();
  const int wv = tid >> 6, ln = tid & 63;
#pragma unroll
  for (int hh = 0; hh < 16; ++hh) {
    const int h = wv * 16 + hh;
    *(uint2*)(out + outMat + (size_t)(h0 + h) * GD + d0 + ln * 4) =
        *(const uint2*)&tl[h][ln * 4];
  }
}

// ---------------- K1b: generic fp32 [E][R][C] -> bf16 [E][C][R] (W2) ----------
__global__ void transpose_kernel(const float* __restrict__ in, u16* __restrict__ out,
                                 int R, int C, int tilesC) {
  __shared__ u16 tile[32][33];
  const int tilesPerMat = (R >> 5) * tilesC;
  const int e  = blockIdx.x / tilesPerMat;
  const int t  = blockIdx.x % tilesPerMat;
  const int tr = t / tilesC, tc = t % tilesC;
  const size_t mat = (size_t)e * R * C;
  const int tx = threadIdx.x & 31, ty = threadIdx.x >> 5;
  const int r0 = tr * 32, c0 = tc * 32;
#pragma unroll
  for (int i = 0; i < 32; i += 8)
    tile[ty + i][tx] = f2bf(in[mat + (size_t)(r0 + ty + i) * C + c0 + tx]);
  __syncthreads();
#pragma unroll
  for (int i = 0; i < 32; i += 8)
    out[mat + (size_t)(c0 + ty + i) * R + r0 + tx] = tile[tx][ty + i];
}

// ---------------- K3: reduce counts2d + scan + tile table (64-row tiles) ------
// 256 threads: 4-way parallel reduce over the 128 block histograms.
__global__ void scan_kernel(const int* __restrict__ counts2d, int* __restrict__ offsets,
                            int* __restrict__ tileHead, int* __restrict__ tileRow,
                            int* __restrict__ nTilesPtr) {
  __shared__ int part[4][GE];
  const int tid = threadIdx.x;
  const int e = tid & 63, q = tid >> 6;
  int c = 0;
  for (int b = q * 32; b < q * 32 + 32; ++b) c += counts2d[b * GE + e];
  part[q][e] = c;
  __syncthreads();
  if (tid < GE) {
    const int ct = part[0][e] + part[1][e] + part[2][e] + part[3][e];
    int inc = ct;
#pragma unroll
    for (int d = 1; d < 64; d <<= 1) { int n = __shfl_up(inc, d); if (e >= d) inc += n; }
    const int off = inc - ct;
    offsets[e] = off;
    if (e == 63) offsets[64] = inc;
    int ntile = (ct + 63) >> 6;
    int inct = ntile;
#pragma unroll
    for (int d = 1; d < 64; d <<= 1) { int n = __shfl_up(inct, d); if (e >= d) inct += n; }
    const int tb = inct - ntile;
    for (int j = 0; j < ntile; ++j) { tileHead[tb + j] = e; tileRow[tb + j] = off + j * 64; }
    if (e == 63) *nTilesPtr = inct;
  }
}

// ---------------- K4: two-phase block scatter ---------------------------------
__global__ void scatter_kernel(const int* __restrict__ prop, const float* __restrict__ mask,
                               const int* __restrict__ offsets, int* __restrict__ cursors_p,
                               int* __restrict__ tokenIds, const int* __restrict__ flag) {
  __shared__ int h[GE];
  __shared__ int basebin[GE];
  const int tid = threadIdx.x;
  const int t = blockIdx.x * 256 + tid;  // grid 128
  if (tid < GE) h[tid] = 0;
  __syncthreads();
  int p = -1, rank = 0;
  if (mask[t] > 0.f) {
    p = getProp(prop, t, *flag);
    rank = atomicAdd(&h[p], 1);
  }
  __syncthreads();
  if (tid < GE && h[tid] > 0) basebin[tid] = atomicAdd(&cursors_p[tid * 16], h[tid]);
  __syncthreads();
  if (p >= 0) tokenIds[offsets[p] + basebin[p] + rank] = t;
}

// ---------------- K5: grouped fused LN + adapter GEMM -------------------------
// 64-row x 256-col tiles. LN fused: per-tile row stats from hs, then per-k-step
// normalize-on-stage into the A buffer (replaces the y workspace round-trip).
// LDS: union(stage 40KB, h 34KB) + sB2 16KB + gamma/beta 6KB + misc ~3.5KB
//   = ~66KB -> 2 blocks/CU.
__global__ __launch_bounds__(256, 2) void adapter_gemm(
    const float* __restrict__ hs, const u16* __restrict__ w1t, const u16* __restrict__ w2t,
    const float* __restrict__ lng, const float* __restrict__ lnb,
    const float* __restrict__ b1, const float* __restrict__ b2,
    const float* __restrict__ w3, const float* __restrict__ b3,
    const float* __restrict__ base, const float* __restrict__ mask,
    const int* __restrict__ tokenIds, const int* __restrict__ offsets,
    const int* __restrict__ tileHead, const int* __restrict__ tileRow,
    const int* __restrict__ nTilesPtr, float* __restrict__ outp) {
  __shared__ union LU {
    struct { u16 A[2][2048]; u16 B[2][8192]; } s;   // staging: [kgrp4][row][8]
    u16 h[17408];                                   // h1 stride 264 / h2 stride 130
  } uni;
  __shared__ u16 sB2[2][4096];   // GEMM2 B staging [kgrp4][n128][8], dbuf
  __shared__ float sBias1[256];
  __shared__ float sBias2[128];
  __shared__ float sW3[2][128];
  __shared__ float sB3[2];
  __shared__ int   sTok[64];
  __shared__ __align__(16) float sGam[GD];
  __shared__ __align__(16) float sBet[GD];
  __shared__ float sMu[64];
  __shared__ float sRstd[64];

  const int tid  = threadIdx.x;
  const int wv   = tid >> 6;
  const int ln   = tid & 63;
  const int l15  = tid & 15;
  const int quad = (tid & 63) >> 4;
  const f32x4 vzero = {0.f, 0.f, 0.f, 0.f};
  const int nt = *nTilesPtr;

  for (int tile = blockIdx.x; tile < nt; tile += gridDim.x) {
    __syncthreads();  // protect LDS/meta reuse across tiles
    const int e  = tileHead[tile];
    const int rs = tileRow[tile];
    const int nRows = min(64, offsets[e + 1] - rs);

    if (tid < 64) sTok[tid] = tokenIds[rs + min(tid, nRows - 1)];
    sBias1[tid] = b1[e * GH + tid];
    if (tid < 128) sBias2[tid] = b2[e * GH2 + tid];
    { const int k = tid >> 1, o = tid & 1; sW3[o][k] = w3[e * GH2 * 2 + k * 2 + o]; }
    if (tid < 2) sB3[tid] = b3[e * 2 + tid];
    __syncthreads();

    const u16* w1e = w1t + (size_t)e * GH * GD;
    const u16* w2e = w2t + (size_t)e * GH2 * GH;

    // prefetch GEMM1 B kt=0 early (in flight during LN stats)
#pragma unroll
    for (int j = 0; j < 4; ++j)
      async16(uni.s.B[0] + wv * 2048 + j * 512,
              w1e + (size_t)(j * 64 + ln) * GD + wv * 8);

    // gamma/beta for this head -> LDS
    if (tid < 192) {
      *(float4*)&sGam[tid * 4] = *(const float4*)(lng + (size_t)e * GD + tid * 4);
      *(float4*)&sBet[tid * 4] = *(const float4*)(lnb + (size_t)e * GD + tid * 4);
    }

    // ---- LN stats: 16 lanes per row, 16 rows per pass, 4 passes ----
#pragma unroll 2
    for (int pass = 0; pass < 4; ++pass) {
      const int row = pass * 16 + (tid >> 4);
      const int l16 = tid & 15;
      const float* xp = hs + (size_t)sTok[row] * GD + l16 * 4;
      float s = 0.f, sq = 0.f;
#pragma unroll
      for (int c = 0; c < 12; ++c) {
        float4 u = *(const float4*)(xp + c * 64);
        s  += u.x + u.y + u.z + u.w;
        sq += u.x*u.x + u.y*u.y + u.z*u.z + u.w*u.w;
      }
#pragma unroll
      for (int d = 1; d < 16; d <<= 1) { s += __shfl_xor(s, d); sq += __shfl_xor(sq, d); }
      if (l16 == 0) {
        const float mu = s * (1.f / 768.f);
        sMu[row] = mu;
        sRstd[row] = rsqrtf(sq * (1.f / 768.f) - mu * mu + 1e-5f);
      }
    }
    __syncthreads();   // sMu/sRstd/sGam/sBet visible

    // per-thread A-staging geometry: 2 rows (r0, r0+32), 4 consecutive k
    const int r0  = tid >> 3;            // 0..31
    const int klo = (tid & 7) * 4;       // 0,4,..,28
    const int kgrp = klo >> 3, kin = klo & 7;
    const float* xA = hs + (size_t)sTok[r0] * GD + klo;
    const float* xB = hs + (size_t)sTok[r0 + 32] * GD + klo;
    const float muA = sMu[r0],      rsA = sRstd[r0];
    const float muB = sMu[r0 + 32], rsB = sRstd[r0 + 32];

#define STAGE_A(K0, PAR) do {                                                   \
    const float4 gv = *(const float4*)&sGam[(K0) + klo];                        \
    const float4 bv = *(const float4*)&sBet[(K0) + klo];                        \
    float4 va = *(const float4*)(xA + (K0));                                    \
    float4 vb = *(const float4*)(xB + (K0));                                    \
    uint2 oa, ob;                                                               \
    oa.x = (u32)f2bf((va.x - muA) * rsA * gv.x + bv.x)                          \
         | ((u32)f2bf((va.y - muA) * rsA * gv.y + bv.y) << 16);                 \
    oa.y = (u32)f2bf((va.z - muA) * rsA * gv.z + bv.z)                          \
         | ((u32)f2bf((va.w - muA) * rsA * gv.w + bv.w) << 16);                 \
    ob.x = (u32)f2bf((vb.x - muB) * rsB * gv.x + bv.x)                          \
         | ((u32)f2bf((vb.y - muB) * rsB * gv.y + bv.y) << 16);                 \
    ob.y = (u32)f2bf((vb.z - muB) * rsB * gv.z + bv.z)                          \
         | ((u32)f2bf((vb.w - muB) * rsB * gv.w + bv.w) << 16);                 \
    *(uint2*)&uni.s.A[PAR][kgrp * 512 + r0 * 8 + kin] = oa;                     \
    *(uint2*)&uni.s.A[PAR][kgrp * 512 + (r0 + 32) * 8 + kin] = ob;              \
  } while (0)

    // ---- GEMM1: ln(hs)[64x768] @ W1t -> h1[64x256]; 24 k-steps, BK=32 ----
    f32x4 acc1[4][4];
#pragma unroll
    for (int f = 0; f < 4; ++f)
#pragma unroll
      for (int g = 0; g < 4; ++g) acc1[f][g] = vzero;

    STAGE_A(0, 0);   // stage A kt=0 (hs rows L2-hot from stats)

    for (int kt = 0; kt < 24; ++kt) {
      __syncthreads();   // drains kt's staging (B vmcnt + A lgkm, issued one iter ago)
      if (kt + 1 < 24) {
        const int k0 = (kt + 1) * 32;
        const int par = (kt + 1) & 1;
#pragma unroll
        for (int j = 0; j < 4; ++j)
          async16(uni.s.B[par] + wv * 2048 + j * 512,
                  w1e + (size_t)(j * 64 + ln) * GD + k0 + wv * 8);
        STAGE_A(k0, par);
      }
      const int par = kt & 1;
      Frag fa[4], fb[4];
#pragma unroll
      for (int f = 0; f < 4; ++f)
        fa[f].u = *(const uint4*)&uni.s.A[par][quad * 512 + (f * 16 + l15) * 8];
#pragma unroll
      for (int g = 0; g < 4; ++g)
        fb[g].u = *(const uint4*)&uni.s.B[par][quad * 2048 + (wv * 64 + g * 16 + l15) * 8];
#pragma unroll
      for (int f = 0; f < 4; ++f)
#pragma unroll
        for (int g = 0; g < 4; ++g)
          acc1[f][g] = __builtin_amdgcn_mfma_f32_16x16x32_bf16(fa[f].b, fb[g].b, acc1[f][g], 0, 0, 0);
    }
    __syncthreads();   // staging region fully read -> uni.h writable

    // prefetch GEMM2 B kt=0 (separate region; overlaps epilogue VALU)
#pragma unroll
    for (int j = 0; j < 2; ++j)
      async16(sB2[0] + wv * 1024 + j * 512,
              w2e + (size_t)(j * 64 + ln) * GH + wv * 8);

    // epilogue 1: +b1, relu -> uni.h (stride 264)
#pragma unroll
    for (int f = 0; f < 4; ++f)
#pragma unroll
      for (int g = 0; g < 4; ++g) {
        const int col = wv * 64 + g * 16 + l15;
        const float bias = sBias1[col];
#pragma unroll
        for (int r = 0; r < 4; ++r) {
          const int row = f * 16 + quad * 4 + r;
          uni.h[row * 264 + col] = f2bf(fmaxf(acc1[f][g][r] + bias, 0.f));
        }
      }

    // ---- GEMM2: h1[64x256] @ W2t -> 64x128; 8 k-steps ----
    f32x4 acc2[4][2];
#pragma unroll
    for (int f = 0; f < 4; ++f)
#pragma unroll
      for (int g = 0; g < 2; ++g) acc2[f][g] = vzero;

    for (int kt = 0; kt < 8; ++kt) {
      __syncthreads();   // drains kt's sB2 loads; also makes h1 visible (kt=0)
      if (kt + 1 < 8) {
        const int k0 = (kt + 1) * 32;
        const int par = (kt + 1) & 1;
#pragma unroll
        for (int j = 0; j < 2; ++j)
          async16(sB2[par] + wv * 1024 + j * 512,
                  w2e + (size_t)(j * 64 + ln) * GH + k0 + wv * 8);
      }
      const int par = kt & 1;
      Frag fa2[4], fb2[2];
#pragma unroll
      for (int f = 0; f < 4; ++f)
        fa2[f].u = *(const uint4*)&uni.h[(f * 16 + l15) * 264 + kt * 32 + quad * 8];
#pragma unroll
      for (int g = 0; g < 2; ++g)
        fb2[g].u = *(const uint4*)&sB2[par][quad * 1024 + (wv * 32 + g * 16 + l15) * 8];
#pragma unroll
      for (int f = 0; f < 4; ++f)
#pragma unroll
        for (int g = 0; g < 2; ++g)
          acc2[f][g] = __builtin_amdgcn_mfma_f32_16x16x32_bf16(fa2[f].b, fb2[g].b, acc2[f][g], 0, 0, 0);
    }
    __syncthreads();   // h1 reads done -> overwrite with h2

    // epilogue 2: +b2, relu -> uni.h as h2 (stride 130: bank-clean for GEMM3)
#pragma unroll
    for (int f = 0; f < 4; ++f)
#pragma unroll
      for (int g = 0; g < 2; ++g) {
        const int col = wv * 32 + g * 16 + l15;
        const float bias = sBias2[col];
#pragma unroll
        for (int r = 0; r < 4; ++r) {
          const int row = f * 16 + quad * 4 + r;
          uni.h[row * 130 + col] = f2bf(fmaxf(acc2[f][g][r] + bias, 0.f));
        }
      }
    __syncthreads();

    // ---------- GEMM3 + residual + mask + scatter-store (fp32) ----------
    const int m = tid >> 1, o = tid & 1;
    if (m < nRows) {
      float a = sB3[o];
      const u16* h2row = &uni.h[m * 130];
#pragma unroll 16
      for (int k = 0; k < 128; ++k) a += bf2f(h2row[k]) * sW3[o][k];
      const int t = sTok[m];
      const float mk = mask[t];
      const float bs = base[t * 2 + o];
      outp[t * 2 + o] = (0.7f * a + 0.3f * bs) * mk;
    }
  }
#undef STAGE_A
}

extern "C" void kernel_launch(void* const* d_in, const int* in_sizes, int n_in,
                              void* d_out, int out_size, void* d_ws, size_t ws_size,
                              hipStream_t stream) {
  const float* hs   = (const float*)d_in[0];
  const float* base = (const float*)d_in[1];
  const int*   prop = (const int*)d_in[2];
  const float* mask = (const float*)d_in[3];
  const float* lng  = (const float*)d_in[4];
  const float* lnb  = (const float*)d_in[5];
  const float* W1   = (const float*)d_in[6];
  const float* b1   = (const float*)d_in[7];
  const float* W2   = (const float*)d_in[8];
  const float* b2   = (const float*)d_in[9];
  const float* W3   = (const float*)d_in[10];
  const float* b3   = (const float*)d_in[11];

  char* ws = (char*)d_ws;
  u16* w1t  = (u16*)(ws + OFF_W1T);
  u16* w2t  = (u16*)(ws + OFF_W2T);
  int* tok  = (int*)(ws + OFF_TOK);
  int* meta = (int*)(ws + OFF_META);
  int* counts2d  = meta;           // 8192 ints
  int* offsets   = meta + 8192;    // 65 ints
  int* tileHead  = meta + 8320;    // 1024 ints
  int* tileRow   = meta + 9344;    // 1024 ints
  int* nTiles    = meta + 10368;
  int* propFlag  = meta + 10369;
  int* cursors_p = meta + 10432;   // 1024 ints (64 bins, 64B-padded)

  setup_kernel<<<128, 256, 0, stream>>>(prop, mask, (u32*)d_out, counts2d,
                                        cursors_p, propFlag);
  transpose_w1<<<768, 256, 0, stream>>>(W1, w1t);
  transpose_kernel<<<64 * 8 * 4, 256, 0, stream>>>(W2, w2t, GH, GH2, 4);
  scan_kernel<<<1, 256, 0, stream>>>(counts2d, offsets, tileHead, tileRow, nTiles);
  scatter_kernel<<<NTOK / 256, 256, 0, stream>>>(prop, mask, offsets, cursors_p, tok, propFlag);
  adapter_gemm<<<640, 256, 0, stream>>>(hs, w1t, w2t, lng, lnb, b1, b2, W3, b3,
                                        base, mask, tok, offsets, tileHead, tileRow,
                                        nTiles, (float*)d_out);
}

// Round 3
// 260.661 us; speedup vs baseline: 1.0953x; 1.0613x over previous
//
#include <hip/hip_runtime.h>
#include <stdint.h>

typedef unsigned short u16;
typedef unsigned int   u32;

#define NTOK   32768      // B*P
#define GD     768
#define GH     256
#define GH2    128
#define GE     64

typedef __bf16 bf16x8 __attribute__((ext_vector_type(8)));
typedef float  f32x4  __attribute__((ext_vector_type(4)));
union Frag { uint4 u; bf16x8 b; };

__device__ __forceinline__ float bf2f(u16 h) {
  union { u32 u; float f; } v; v.u = ((u32)h) << 16; return v.f;
}
__device__ __forceinline__ u16 f2bf(float f) {
  union { float f; u32 u; } v; v.f = f;
  u32 r = (v.u + 0x7fffu + ((v.u >> 16) & 1u)) >> 16;
  return (u16)r;
}

__device__ __forceinline__ void async16(void* lds, const void* g) {
  __builtin_amdgcn_global_load_lds(
      (const __attribute__((address_space(1))) void*)g,
      (__attribute__((address_space(3))) void*)lds, 16, 0, 0);
}

__device__ __forceinline__ int getProp(const int* p32, int t, int is64) {
  return is64 ? p32[2 * t] : p32[t];
}

// ---------------- workspace layout (bytes) ----------------
// W1T/W2T are stored PRE-TILED in the GEMM's LDS staging order:
//   W1T: [e][kt24][kgrp4][row256][kin8]  (row = H index, k = kt*32+kgrp*8+kin)
//   W2T: [e][kt8][kgrp4][row128][kin8]   (row = H2 index, k over GH)
// so every global_load_lds is 64 lanes x 16 B fully contiguous.
static const size_t OFF_W1T  = 0;            // bf16 64*256*768*2 = 25165824
static const size_t OFF_W2T  = 25165824;     // bf16 64*128*256*2 = 4194304
static const size_t OFF_TOK  = 29360128;     // int  NTOK*4 = 131072
static const size_t OFF_META = 29491200;     // ints (~46 KB)

// ---------------- K0: zero out + prop-dtype flag + per-block histogram -------
__global__ void setup_kernel(const int* __restrict__ prop, const float* __restrict__ mask,
                             u32* __restrict__ outz, int* __restrict__ counts2d,
                             int* __restrict__ cursors_p, int* __restrict__ flagp) {
  __shared__ int h[GE];
  __shared__ int vOr;
  const int b = blockIdx.x;                 // grid 128
  const int tid = threadIdx.x;
  outz[b * 512 + tid] = 0u;
  outz[b * 512 + 256 + tid] = 0u;
  if (b < 4) cursors_p[b * 256 + tid] = 0;
  if (tid < GE) h[tid] = 0;
  if (tid == 0) vOr = 0;
  __syncthreads();
  int v = prop[2 * tid + 1] | prop[2 * (tid + 256) + 1];
  if (v) atomicOr(&vOr, 1);
  __syncthreads();
  const int is64 = (vOr == 0) ? 1 : 0;
  if (b == 0 && tid == 0) *flagp = is64;
  const int t = b * 256 + tid;
  if (mask[t] > 0.f) atomicAdd(&h[getProp(prop, t, is64)], 1);
  __syncthreads();
  if (tid < GE) counts2d[b * GE + tid] = h[tid];
}

// ---------------- K1a: W1 fp32 [64][768][256] -> bf16 tiled -------------------
// out element (h row in [0,256), d k in [0,768)):
//   off = kt*8192 + kgrp*2048 + h*8 + kin,  kt=d>>5, kgrp=(d>>3)&3, kin=d&7
__global__ void transpose_w1(const float* __restrict__ in, u16* __restrict__ out) {
  __shared__ u16 tl[64][260];               // [h][d], 33.3 KB
  const int bid = blockIdx.x;               // grid 64*3*4 = 768
  const int e  = bid / 12, r = bid % 12;
  const int d0 = (r / 4) * 256, h0 = (r % 4) * 64;
  const int tid = threadIdx.x;
  const size_t inMat = (size_t)e * GD * GH;
  const size_t outMat = (size_t)e * GH * GD;
  const int h_l = (tid & 15) * 4, d_l = tid >> 4;
#pragma unroll
  for (int dd = 0; dd < 16; ++dd) {
    const int d = d_l + dd * 16;
    float4 v = *(const float4*)(in + inMat + (size_t)(d0 + d) * GH + h0 + h_l);
    tl[h_l + 0][d] = f2bf(v.x);
    tl[h_l + 1][d] = f2bf(v.y);
    tl[h_l + 2][d] = f2bf(v.z);
    tl[h_l + 3][d] = f2bf(v.w);
  }
  __syncthreads();
  const int wv = tid >> 6, ln = tid & 63;
  const int d_glob = d0 + ln * 4;           // 4 consecutive k within one kin-octet
  const size_t tbase = outMat + (size_t)(d_glob >> 5) * 8192 +
                       (size_t)((d_glob >> 3) & 3) * 2048 + (d_glob & 7);
#pragma unroll
  for (int hh = 0; hh < 16; ++hh) {
    const int h = wv * 16 + hh;
    *(uint2*)(out + tbase + (size_t)(h0 + h) * 8) = *(const uint2*)&tl[h][ln * 4];
  }
}

// ---------------- K1b: W2 fp32 [E][256][128] -> bf16 tiled --------------------
// out element (row in [0,128), k in [0,256)):
//   off = (k>>5)*4096 + ((k>>3)&3)*1024 + row*8 + (k&7)
__global__ void transpose_w2(const float* __restrict__ in, u16* __restrict__ out) {
  __shared__ u16 tile[32][33];
  const int tilesPerMat = 32;               // (256/32) * (128/32)
  const int e  = blockIdx.x / tilesPerMat;
  const int t  = blockIdx.x % tilesPerMat;
  const int tr = t / 4, tc = t % 4;         // tr: k-tile, tc: row-tile
  const size_t mat = (size_t)e * GH * GH2;
  const int tx = threadIdx.x & 31, ty = threadIdx.x >> 5;
  const int r0 = tr * 32, c0 = tc * 32;
#pragma unroll
  for (int i = 0; i < 32; i += 8)
    tile[ty + i][tx] = f2bf(in[mat + (size_t)(r0 + ty + i) * GH2 + c0 + tx]);
  __syncthreads();
  const int k = r0 + tx;
  const size_t kbase = mat + (size_t)(k >> 5) * 4096 +
                       (size_t)((k >> 3) & 3) * 1024 + (k & 7);
#pragma unroll
  for (int i = 0; i < 32; i += 8)
    out[kbase + (size_t)(c0 + ty + i) * 8] = tile[tx][ty + i];
}

// ---------------- K3: reduce counts2d + scan + tile table (64-row tiles) ------
__global__ void scan_kernel(const int* __restrict__ counts2d, int* __restrict__ offsets,
                            int* __restrict__ tileHead, int* __restrict__ tileRow,
                            int* __restrict__ nTilesPtr) {
  __shared__ int part[4][GE];
  const int tid = threadIdx.x;
  const int e = tid & 63, q = tid >> 6;
  int c = 0;
  for (int b = q * 32; b < q * 32 + 32; ++b) c += counts2d[b * GE + e];
  part[q][e] = c;
  __syncthreads();
  if (tid < GE) {
    const int ct = part[0][e] + part[1][e] + part[2][e] + part[3][e];
    int inc = ct;
#pragma unroll
    for (int d = 1; d < 64; d <<= 1) { int n = __shfl_up(inc, d); if (e >= d) inc += n; }
    const int off = inc - ct;
    offsets[e] = off;
    if (e == 63) offsets[64] = inc;
    int ntile = (ct + 63) >> 6;
    int inct = ntile;
#pragma unroll
    for (int d = 1; d < 64; d <<= 1) { int n = __shfl_up(inct, d); if (e >= d) inct += n; }
    const int tb = inct - ntile;
    for (int j = 0; j < ntile; ++j) { tileHead[tb + j] = e; tileRow[tb + j] = off + j * 64; }
    if (e == 63) *nTilesPtr = inct;
  }
}

// ---------------- K4: two-phase block scatter ---------------------------------
__global__ void scatter_kernel(const int* __restrict__ prop, const float* __restrict__ mask,
                               const int* __restrict__ offsets, int* __restrict__ cursors_p,
                               int* __restrict__ tokenIds, const int* __restrict__ flag) {
  __shared__ int h[GE];
  __shared__ int basebin[GE];
  const int tid = threadIdx.x;
  const int t = blockIdx.x * 256 + tid;  // grid 128
  if (tid < GE) h[tid] = 0;
  __syncthreads();
  int p = -1, rank = 0;
  if (mask[t] > 0.f) {
    p = getProp(prop, t, *flag);
    rank = atomicAdd(&h[p], 1);
  }
  __syncthreads();
  if (tid < GE && h[tid] > 0) basebin[tid] = atomicAdd(&cursors_p[tid * 16], h[tid]);
  __syncthreads();
  if (p >= 0) tokenIds[offsets[p] + basebin[p] + rank] = t;
}

// ---------------- K5: grouped fused LN + adapter GEMM -------------------------
// 64-row x 256-col tiles, pre-tiled B (fully coalesced global_load_lds),
// bijective XCD swizzle so same-head tiles share an XCD L2.
__global__ __launch_bounds__(256, 2) void adapter_gemm(
    const float* __restrict__ hs, const u16* __restrict__ w1t, const u16* __restrict__ w2t,
    const float* __restrict__ lng, const float* __restrict__ lnb,
    const float* __restrict__ b1, const float* __restrict__ b2,
    const float* __restrict__ w3, const float* __restrict__ b3,
    const float* __restrict__ base, const float* __restrict__ mask,
    const int* __restrict__ tokenIds, const int* __restrict__ offsets,
    const int* __restrict__ tileHead, const int* __restrict__ tileRow,
    const int* __restrict__ nTilesPtr, float* __restrict__ outp) {
  __shared__ union LU {
    struct { u16 A[2][2048]; u16 B[2][8192]; } s;   // staging: [kgrp4][row][8]
    u16 h[17408];                                   // h1 stride 264 / h2 stride 130
  } uni;
  __shared__ u16 sB2[2][4096];   // GEMM2 B staging [kgrp4][n128][8], dbuf
  __shared__ float sBias1[256];
  __shared__ float sBias2[128];
  __shared__ float sW3[2][128];
  __shared__ float sB3[2];
  __shared__ int   sTok[64];
  __shared__ __align__(16) float sGam[GD];
  __shared__ __align__(16) float sBet[GD];
  __shared__ float sMu[64];
  __shared__ float sRstd[64];

  const int tid  = threadIdx.x;
  const int wv   = tid >> 6;
  const int ln   = tid & 63;
  const int l15  = tid & 15;
  const int quad = (tid & 63) >> 4;
  const f32x4 vzero = {0.f, 0.f, 0.f, 0.f};
  const int nt = *nTilesPtr;
  // bijective XCD chunking (m204): consecutive tiles (same head) -> same XCD
  const int qq = nt >> 3, rr = nt & 7;

  for (int i = blockIdx.x; i < nt; i += gridDim.x) {
    const int x = i & 7, s = i >> 3;
    const int tile = (x < rr ? x * (qq + 1) : rr * (qq + 1) + (x - rr) * qq) + s;

    __syncthreads();  // protect LDS/meta reuse across tiles
    const int e  = tileHead[tile];
    const int rs = tileRow[tile];
    const int nRows = min(64, offsets[e + 1] - rs);

    if (tid < 64) sTok[tid] = tokenIds[rs + min(tid, nRows - 1)];
    sBias1[tid] = b1[e * GH + tid];
    if (tid < 128) sBias2[tid] = b2[e * GH2 + tid];
    { const int k = tid >> 1, o = tid & 1; sW3[o][k] = w3[e * GH2 * 2 + k * 2 + o]; }
    if (tid < 2) sB3[tid] = b3[e * 2 + tid];
    __syncthreads();

    const u16* w1e = w1t + (size_t)e * GH * GD;   // tiled [kt24][kgrp4][256][8]
    const u16* w2e = w2t + (size_t)e * GH2 * GH;  // tiled [kt8][kgrp4][128][8]

    // prefetch GEMM1 B kt=0 early (in flight during LN stats); coalesced 1KB/instr
#pragma unroll
    for (int j = 0; j < 4; ++j)
      async16(uni.s.B[0] + wv * 2048 + j * 512,
              w1e + wv * 2048 + j * 512 + ln * 8);

    // gamma/beta for this head -> LDS
    if (tid < 192) {
      *(float4*)&sGam[tid * 4] = *(const float4*)(lng + (size_t)e * GD + tid * 4);
      *(float4*)&sBet[tid * 4] = *(const float4*)(lnb + (size_t)e * GD + tid * 4);
    }

    // ---- LN stats: 16 lanes per row, 16 rows per pass, 4 passes ----
#pragma unroll 2
    for (int pass = 0; pass < 4; ++pass) {
      const int row = pass * 16 + (tid >> 4);
      const int l16 = tid & 15;
      const float* xp = hs + (size_t)sTok[row] * GD + l16 * 4;
      float sm = 0.f, sq = 0.f;
#pragma unroll
      for (int c = 0; c < 12; ++c) {
        float4 u = *(const float4*)(xp + c * 64);
        sm += u.x + u.y + u.z + u.w;
        sq += u.x*u.x + u.y*u.y + u.z*u.z + u.w*u.w;
      }
#pragma unroll
      for (int d = 1; d < 16; d <<= 1) { sm += __shfl_xor(sm, d); sq += __shfl_xor(sq, d); }
      if (l16 == 0) {
        const float mu = sm * (1.f / 768.f);
        sMu[row] = mu;
        sRstd[row] = rsqrtf(sq * (1.f / 768.f) - mu * mu + 1e-5f);
      }
    }
    __syncthreads();   // sMu/sRstd/sGam/sBet visible

    // per-thread A-staging geometry: 2 rows (r0, r0+32), 4 consecutive k
    const int r0  = tid >> 3;            // 0..31
    const int klo = (tid & 7) * 4;       // 0,4,..,28
    const int kgrp = klo >> 3, kin = klo & 7;
    const float* xA = hs + (size_t)sTok[r0] * GD + klo;
    const float* xB = hs + (size_t)sTok[r0 + 32] * GD + klo;
    const float muA = sMu[r0],      rsA = sRstd[r0];
    const float muB = sMu[r0 + 32], rsB = sRstd[r0 + 32];

#define STAGE_A(K0, PAR) do {                                                   \
    const float4 gv = *(const float4*)&sGam[(K0) + klo];                        \
    const float4 bv = *(const float4*)&sBet[(K0) + klo];                        \
    float4 va = *(const float4*)(xA + (K0));                                    \
    float4 vb = *(const float4*)(xB + (K0));                                    \
    uint2 oa, ob;                                                               \
    oa.x = (u32)f2bf((va.x - muA) * rsA * gv.x + bv.x)                          \
         | ((u32)f2bf((va.y - muA) * rsA * gv.y + bv.y) << 16);                 \
    oa.y = (u32)f2bf((va.z - muA) * rsA * gv.z + bv.z)                          \
         | ((u32)f2bf((va.w - muA) * rsA * gv.w + bv.w) << 16);                 \
    ob.x = (u32)f2bf((vb.x - muB) * rsB * gv.x + bv.x)                          \
         | ((u32)f2bf((vb.y - muB) * rsB * gv.y + bv.y) << 16);                 \
    ob.y = (u32)f2bf((vb.z - muB) * rsB * gv.z + bv.z)                          \
         | ((u32)f2bf((vb.w - muB) * rsB * gv.w + bv.w) << 16);                 \
    *(uint2*)&uni.s.A[PAR][kgrp * 512 + r0 * 8 + kin] = oa;                     \
    *(uint2*)&uni.s.A[PAR][kgrp * 512 + (r0 + 32) * 8 + kin] = ob;              \
  } while (0)

    // ---- GEMM1: ln(hs)[64x768] @ W1t -> h1[64x256]; 24 k-steps, BK=32 ----
    f32x4 acc1[4][4];
#pragma unroll
    for (int f = 0; f < 4; ++f)
#pragma unroll
      for (int g = 0; g < 4; ++g) acc1[f][g] = vzero;

    STAGE_A(0, 0);   // stage A kt=0 (hs rows L2-hot from stats)

    for (int kt = 0; kt < 24; ++kt) {
      __syncthreads();   // drains kt's staging (issued one iter ago)
      if (kt + 1 < 24) {
        const int par = (kt + 1) & 1;
#pragma unroll
        for (int j = 0; j < 4; ++j)
          async16(uni.s.B[par] + wv * 2048 + j * 512,
                  w1e + (kt + 1) * 8192 + wv * 2048 + j * 512 + ln * 8);
        STAGE_A((kt + 1) * 32, par);
      }
      const int par = kt & 1;
      Frag fa[4], fb[4];
#pragma unroll
      for (int f = 0; f < 4; ++f)
        fa[f].u = *(const uint4*)&uni.s.A[par][quad * 512 + (f * 16 + l15) * 8];
#pragma unroll
      for (int g = 0; g < 4; ++g)
        fb[g].u = *(const uint4*)&uni.s.B[par][quad * 2048 + (wv * 64 + g * 16 + l15) * 8];
#pragma unroll
      for (int f = 0; f < 4; ++f)
#pragma unroll
        for (int g = 0; g < 4; ++g)
          acc1[f][g] = __builtin_amdgcn_mfma_f32_16x16x32_bf16(fa[f].b, fb[g].b, acc1[f][g], 0, 0, 0);
    }
    __syncthreads();   // staging region fully read -> uni.h writable

    // prefetch GEMM2 B kt=0 (separate region; overlaps epilogue VALU)
#pragma unroll
    for (int j = 0; j < 2; ++j)
      async16(sB2[0] + wv * 1024 + j * 512,
              w2e + wv * 1024 + j * 512 + ln * 8);

    // epilogue 1: +b1, relu -> uni.h (stride 264)
#pragma unroll
    for (int f = 0; f < 4; ++f)
#pragma unroll
      for (int g = 0; g < 4; ++g) {
        const int col = wv * 64 + g * 16 + l15;
        const float bias = sBias1[col];
#pragma unroll
        for (int r = 0; r < 4; ++r) {
          const int row = f * 16 + quad * 4 + r;
          uni.h[row * 264 + col] = f2bf(fmaxf(acc1[f][g][r] + bias, 0.f));
        }
      }

    // ---- GEMM2: h1[64x256] @ W2t -> 64x128; 8 k-steps ----
    f32x4 acc2[4][2];
#pragma unroll
    for (int f = 0; f < 4; ++f)
#pragma unroll
      for (int g = 0; g < 2; ++g) acc2[f][g] = vzero;

    for (int kt = 0; kt < 8; ++kt) {
      __syncthreads();   // drains kt's sB2 loads; also makes h1 visible (kt=0)
      if (kt + 1 < 8) {
        const int par = (kt + 1) & 1;
#pragma unroll
        for (int j = 0; j < 2; ++j)
          async16(sB2[par] + wv * 1024 + j * 512,
                  w2e + (kt + 1) * 4096 + wv * 1024 + j * 512 + ln * 8);
      }
      const int par = kt & 1;
      Frag fa2[4], fb2[2];
#pragma unroll
      for (int f = 0; f < 4; ++f)
        fa2[f].u = *(const uint4*)&uni.h[(f * 16 + l15) * 264 + kt * 32 + quad * 8];
#pragma unroll
      for (int g = 0; g < 2; ++g)
        fb2[g].u = *(const uint4*)&sB2[par][quad * 1024 + (wv * 32 + g * 16 + l15) * 8];
#pragma unroll
      for (int f = 0; f < 4; ++f)
#pragma unroll
        for (int g = 0; g < 2; ++g)
          acc2[f][g] = __builtin_amdgcn_mfma_f32_16x16x32_bf16(fa2[f].b, fb2[g].b, acc2[f][g], 0, 0, 0);
    }
    __syncthreads();   // h1 reads done -> overwrite with h2

    // epilogue 2: +b2, relu -> uni.h as h2 (stride 130: bank-clean for GEMM3)
#pragma unroll
    for (int f = 0; f < 4; ++f)
#pragma unroll
      for (int g = 0; g < 2; ++g) {
        const int col = wv * 32 + g * 16 + l15;
        const float bias = sBias2[col];
#pragma unroll
        for (int r = 0; r < 4; ++r) {
          const int row = f * 16 + quad * 4 + r;
          uni.h[row * 130 + col] = f2bf(fmaxf(acc2[f][g][r] + bias, 0.f));
        }
      }
    __syncthreads();

    // ---------- GEMM3 + residual + mask + scatter-store (fp32) ----------
    const int m = tid >> 1, o = tid & 1;
    if (m < nRows) {
      float a = sB3[o];
      const u16* h2row = &uni.h[m * 130];
#pragma unroll 16
      for (int k = 0; k < 128; ++k) a += bf2f(h2row[k]) * sW3[o][k];
      const int t = sTok[m];
      const float mk = mask[t];
      const float bs = base[t * 2 + o];
      outp[t * 2 + o] = (0.7f * a + 0.3f * bs) * mk;
    }
  }
#undef STAGE_A
}

extern "C" void kernel_launch(void* const* d_in, const int* in_sizes, int n_in,
                              void* d_out, int out_size, void* d_ws, size_t ws_size,
                              hipStream_t stream) {
  const float* hs   = (const float*)d_in[0];
  const float* base = (const float*)d_in[1];
  const int*   prop = (const int*)d_in[2];
  const float* mask = (const float*)d_in[3];
  const float* lng  = (const float*)d_in[4];
  const float* lnb  = (const float*)d_in[5];
  const float* W1   = (const float*)d_in[6];
  const float* b1   = (const float*)d_in[7];
  const float* W2   = (const float*)d_in[8];
  const float* b2   = (const float*)d_in[9];
  const float* W3   = (const float*)d_in[10];
  const float* b3   = (const float*)d_in[11];

  char* ws = (char*)d_ws;
  u16* w1t  = (u16*)(ws + OFF_W1T);
  u16* w2t  = (u16*)(ws + OFF_W2T);
  int* tok  = (int*)(ws + OFF_TOK);
  int* meta = (int*)(ws + OFF_META);
  int* counts2d  = meta;           // 8192 ints
  int* offsets   = meta + 8192;    // 65 ints
  int* tileHead  = meta + 8320;    // 1024 ints
  int* tileRow   = meta + 9344;    // 1024 ints
  int* nTiles    = meta + 10368;
  int* propFlag  = meta + 10369;
  int* cursors_p = meta + 10432;   // 1024 ints (64 bins, 64B-padded)

  setup_kernel<<<128, 256, 0, stream>>>(prop, mask, (u32*)d_out, counts2d,
                                        cursors_p, propFlag);
  transpose_w1<<<768, 256, 0, stream>>>(W1, w1t);
  transpose_w2<<<64 * 32, 256, 0, stream>>>(W2, w2t);
  scan_kernel<<<1, 256, 0, stream>>>(counts2d, offsets, tileHead, tileRow, nTiles);
  scatter_kernel<<<NTOK / 256, 256, 0, stream>>>(prop, mask, offsets, cursors_p, tok, propFlag);
  adapter_gemm<<<640, 256, 0, stream>>>(hs, w1t, w2t, lng, lnb, b1, b2, W3, b3,
                                        base, mask, tok, offsets, tileHead, tileRow,
                                        nTiles, (float*)d_out);
}

// Round 5
// 255.050 us; speedup vs baseline: 1.1194x; 1.0220x over previous
//
#include <hip/hip_runtime.h>
#include <stdint.h>

typedef unsigned short u16;
typedef unsigned int   u32;

#define NTOK   32768      // B*P
#define GD     768
#define GH     256
#define GH2    128
#define GE     64

typedef __bf16 bf16x8 __attribute__((ext_vector_type(8)));
typedef float  f32x4  __attribute__((ext_vector_type(4)));
union Frag { uint4 u; bf16x8 b; };

__device__ __forceinline__ float bf2f(u16 h) {
  union { u32 u; float f; } v; v.u = ((u32)h) << 16; return v.f;
}
__device__ __forceinline__ u16 f2bf(float f) {
  union { float f; u32 u; } v; v.f = f;
  u32 r = (v.u + 0x7fffu + ((v.u >> 16) & 1u)) >> 16;
  return (u16)r;
}

__device__ __forceinline__ void async16(void* lds, const void* g) {
  __builtin_amdgcn_global_load_lds(
      (const __attribute__((address_space(1))) void*)g,
      (__attribute__((address_space(3))) void*)lds, 16, 0, 0);
}

// raw barrier: drain LDS ops only (NOT vmcnt — keeps prefetch in flight)
__device__ __forceinline__ void bar_lds() {
  asm volatile("s_waitcnt lgkmcnt(0)" ::: "memory");
  __builtin_amdgcn_sched_barrier(0);
  __builtin_amdgcn_s_barrier();
  __builtin_amdgcn_sched_barrier(0);
}

__device__ __forceinline__ int getProp(const int* p32, int t, int is64) {
  return is64 ? p32[2 * t] : p32[t];
}

// ---------------- workspace layout (bytes) ----------------
// W1T/W2T stored PRE-TILED in LDS staging order:
//   W1T: [e][kt24][kgrp4][row256][kin8], W2T: [e][kt8][kgrp4][row128][kin8]
static const size_t OFF_W1T  = 0;            // bf16 64*256*768*2 = 25165824
static const size_t OFF_W2T  = 25165824;     // bf16 64*128*256*2 = 4194304
static const size_t OFF_TOK  = 29360128;     // int  NTOK*4 = 131072
static const size_t OFF_META = 29491200;     // ints (~46 KB)

// ---------------- K0: zero out + prop-dtype flag + per-block histogram -------
__global__ void setup_kernel(const int* __restrict__ prop, const float* __restrict__ mask,
                             u32* __restrict__ outz, int* __restrict__ counts2d,
                             int* __restrict__ cursors_p, int* __restrict__ flagp) {
  __shared__ int h[GE];
  __shared__ int vOr;
  const int b = blockIdx.x;                 // grid 128
  const int tid = threadIdx.x;
  outz[b * 512 + tid] = 0u;
  outz[b * 512 + 256 + tid] = 0u;
  if (b < 4) cursors_p[b * 256 + tid] = 0;
  if (tid < GE) h[tid] = 0;
  if (tid == 0) vOr = 0;
  __syncthreads();
  int v = prop[2 * tid + 1] | prop[2 * (tid + 256) + 1];
  if (v) atomicOr(&vOr, 1);
  __syncthreads();
  const int is64 = (vOr == 0) ? 1 : 0;
  if (b == 0 && tid == 0) *flagp = is64;
  const int t = b * 256 + tid;
  if (mask[t] > 0.f) atomicAdd(&h[getProp(prop, t, is64)], 1);
  __syncthreads();
  if (tid < GE) counts2d[b * GE + tid] = h[tid];
}

// ---------------- K1a: W1 fp32 [64][768][256] -> bf16 tiled -------------------
__global__ void transpose_w1(const float* __restrict__ in, u16* __restrict__ out) {
  __shared__ u16 tl[64][260];               // [h][d], 33.3 KB
  const int bid = blockIdx.x;               // grid 64*3*4 = 768
  const int e  = bid / 12, r = bid % 12;
  const int d0 = (r / 4) * 256, h0 = (r % 4) * 64;
  const int tid = threadIdx.x;
  const size_t inMat = (size_t)e * GD * GH;
  const size_t outMat = (size_t)e * GH * GD;
  const int h_l = (tid & 15) * 4, d_l = tid >> 4;
#pragma unroll
  for (int dd = 0; dd < 16; ++dd) {
    const int d = d_l + dd * 16;
    float4 v = *(const float4*)(in + inMat + (size_t)(d0 + d) * GH + h0 + h_l);
    tl[h_l + 0][d] = f2bf(v.x);
    tl[h_l + 1][d] = f2bf(v.y);
    tl[h_l + 2][d] = f2bf(v.z);
    tl[h_l + 3][d] = f2bf(v.w);
  }
  __syncthreads();
  const int wv = tid >> 6, ln = tid & 63;
  const int d_glob = d0 + ln * 4;
  const size_t tbase = outMat + (size_t)(d_glob >> 5) * 8192 +
                       (size_t)((d_glob >> 3) & 3) * 2048 + (d_glob & 7);
#pragma unroll
  for (int hh = 0; hh < 16; ++hh) {
    const int h = wv * 16 + hh;
    *(uint2*)(out + tbase + (size_t)(h0 + h) * 8) = *(const uint2*)&tl[h][ln * 4];
  }
}

// ---------------- K1b: W2 fp32 [E][256][128] -> bf16 tiled --------------------
__global__ void transpose_w2(const float* __restrict__ in, u16* __restrict__ out) {
  __shared__ u16 tile[32][33];
  const int tilesPerMat = 32;               // (256/32) * (128/32)
  const int e  = blockIdx.x / tilesPerMat;
  const int t  = blockIdx.x % tilesPerMat;
  const int tr = t / 4, tc = t % 4;         // tr: k-tile, tc: row-tile
  const size_t mat = (size_t)e * GH * GH2;
  const int tx = threadIdx.x & 31, ty = threadIdx.x >> 5;
  const int r0 = tr * 32, c0 = tc * 32;
#pragma unroll
  for (int i = 0; i < 32; i += 8)
    tile[ty + i][tx] = f2bf(in[mat + (size_t)(r0 + ty + i) * GH2 + c0 + tx]);
  __syncthreads();
  const int k = r0 + tx;
  const size_t kbase = mat + (size_t)(k >> 5) * 4096 +
                       (size_t)((k >> 3) & 3) * 1024 + (k & 7);
#pragma unroll
  for (int i = 0; i < 32; i += 8)
    out[kbase + (size_t)(c0 + ty + i) * 8] = tile[tx][ty + i];
}

// ---------------- K3: reduce counts2d + scan + tile table (64-row tiles) ------
__global__ void scan_kernel(const int* __restrict__ counts2d, int* __restrict__ offsets,
                            int* __restrict__ tileHead, int* __restrict__ tileRow,
                            int* __restrict__ nTilesPtr) {
  __shared__ int part[4][GE];
  const int tid = threadIdx.x;
  const int e = tid & 63, q = tid >> 6;
  int c = 0;
  for (int b = q * 32; b < q * 32 + 32; ++b) c += counts2d[b * GE + e];
  part[q][e] = c;
  __syncthreads();
  if (tid < GE) {
    const int ct = part[0][e] + part[1][e] + part[2][e] + part[3][e];
    int inc = ct;
#pragma unroll
    for (int d = 1; d < 64; d <<= 1) { int n = __shfl_up(inc, d); if (e >= d) inc += n; }
    const int off = inc - ct;
    offsets[e] = off;
    if (e == 63) offsets[64] = inc;
    int ntile = (ct + 63) >> 6;
    int inct = ntile;
#pragma unroll
    for (int d = 1; d < 64; d <<= 1) { int n = __shfl_up(inct, d); if (e >= d) inct += n; }
    const int tb = inct - ntile;
    for (int j = 0; j < ntile; ++j) { tileHead[tb + j] = e; tileRow[tb + j] = off + j * 64; }
    if (e == 63) *nTilesPtr = inct;
  }
}

// ---------------- K4: two-phase block scatter ---------------------------------
__global__ void scatter_kernel(const int* __restrict__ prop, const float* __restrict__ mask,
                               const int* __restrict__ offsets, int* __restrict__ cursors_p,
                               int* __restrict__ tokenIds, const int* __restrict__ flag) {
  __shared__ int h[GE];
  __shared__ int basebin[GE];
  const int tid = threadIdx.x;
  const int t = blockIdx.x * 256 + tid;  // grid 128
  if (tid < GE) h[tid] = 0;
  __syncthreads();
  int p = -1, rank = 0;
  if (mask[t] > 0.f) {
    p = getProp(prop, t, *flag);
    rank = atomicAdd(&h[p], 1);
  }
  __syncthreads();
  if (tid < GE && h[tid] > 0) basebin[tid] = atomicAdd(&cursors_p[tid * 16], h[tid]);
  __syncthreads();
  if (p >= 0) tokenIds[offsets[p] + basebin[p] + rank] = t;
}

// ---------------- K5: grouped fused LN + adapter GEMM -------------------------
// 64x256 tiles. GEMM1: 3-buffer staging, raw barriers, counted vmcnt —
// vmcnt(6) while issuing (kt<22), vmcnt(0) in the tail so B(23) is guaranteed
// in LDS before its read (fixes the end-of-pipeline race). GEMM2: B in
// registers, zero barriers. LDS ~71 KB -> 2 blocks/CU.
__global__ __launch_bounds__(256, 2) void adapter_gemm(
    const float* __restrict__ hs, const u16* __restrict__ w1t, const u16* __restrict__ w2t,
    const float* __restrict__ lng, const float* __restrict__ lnb,
    const float* __restrict__ b1, const float* __restrict__ b2,
    const float* __restrict__ w3, const float* __restrict__ b3,
    const float* __restrict__ base, const float* __restrict__ mask,
    const int* __restrict__ tokenIds, const int* __restrict__ offsets,
    const int* __restrict__ tileHead, const int* __restrict__ tileRow,
    const int* __restrict__ nTilesPtr, float* __restrict__ outp) {
  __shared__ union LU {
    struct { u16 A[3][2048]; u16 B[3][8192]; } s;   // 61,440 B staging (3-buf)
    u16 h[17408];                                   // h1 stride 264 / h2 stride 130
  } uni;
  __shared__ float sBias1[256];
  __shared__ float sBias2[128];
  __shared__ float sW3[2][128];
  __shared__ float sB3[2];
  __shared__ int   sTok[64];
  __shared__ __align__(16) float sGam[GD];
  __shared__ __align__(16) float sBet[GD];
  __shared__ float sMu[64];
  __shared__ float sRstd[64];

  const int tid  = threadIdx.x;
  const int wv   = tid >> 6;
  const int ln   = tid & 63;
  const int l15  = tid & 15;
  const int quad = (tid & 63) >> 4;
  const f32x4 vzero = {0.f, 0.f, 0.f, 0.f};
  const int nt = *nTilesPtr;
  // bijective XCD chunking: consecutive tiles (same head) -> same XCD
  const int qq = nt >> 3, rr = nt & 7;

  for (int i = blockIdx.x; i < nt; i += gridDim.x) {
    const int x = i & 7, s = i >> 3;
    const int tile = (x < rr ? x * (qq + 1) : rr * (qq + 1) + (x - rr) * qq) + s;

    __syncthreads();  // tile top: full drain (prev GEMM3 reads/stores done)
    const int e  = tileHead[tile];
    const int rs = tileRow[tile];
    const int nRows = min(64, offsets[e + 1] - rs);

    if (tid < 64) sTok[tid] = tokenIds[rs + min(tid, nRows - 1)];
    sBias1[tid] = b1[e * GH + tid];
    if (tid < 128) sBias2[tid] = b2[e * GH2 + tid];
    { const int k = tid >> 1, o = tid & 1; sW3[o][k] = w3[e * GH2 * 2 + k * 2 + o]; }
    if (tid < 2) sB3[tid] = b3[e * 2 + tid];
    __syncthreads();

    const u16* w1e = w1t + (size_t)e * GH * GD;   // tiled [kt24][kgrp4][256][8]
    const u16* w2e = w2t + (size_t)e * GH2 * GH;  // tiled [kt8][kgrp4][128][8]

    // gamma/beta -> LDS (self-draining: nothing older outstanding)
    if (tid < 192) {
      *(float4*)&sGam[tid * 4] = *(const float4*)(lng + (size_t)e * GD + tid * 4);
      *(float4*)&sBet[tid * 4] = *(const float4*)(lnb + (size_t)e * GD + tid * 4);
    }

    // per-thread A geometry: rows (r0, r0+32), 4 consecutive k
    const int r0  = tid >> 3;            // 0..31
    const int klo = (tid & 7) * 4;       // 0,4,..,28
    const int kgrp = klo >> 3, kin = klo & 7;
    const float* xA = hs + (size_t)sTok[r0] * GD + klo;
    const float* xB = hs + (size_t)sTok[r0 + 32] * GD + klo;

#define ISSUE_B(S, KT) do {                                                     \
    u16* _bb = uni.s.B[S] + wv * 2048;                                          \
    const u16* _gg = w1e + (KT) * 8192 + wv * 2048 + ln * 8;                    \
    async16(_bb,        _gg);        async16(_bb + 512,  _gg + 512);            \
    async16(_bb + 1024, _gg + 1024); async16(_bb + 1536, _gg + 1536);           \
  } while (0)

    float4 pAa[2], pAb[2];
    // prologue: B(0), A(0), B(1), A(1) in flight during LN stats
    ISSUE_B(0, 0);
    __builtin_amdgcn_sched_barrier(0);
    pAa[0] = *(const float4*)(xA);
    pAb[0] = *(const float4*)(xB);
    ISSUE_B(1, 1);
    __builtin_amdgcn_sched_barrier(0);
    pAa[1] = *(const float4*)(xA + 32);
    pAb[1] = *(const float4*)(xB + 32);

    // ---- LN stats: 16 lanes per row, 16 rows per pass, 4 passes ----
#pragma unroll 2
    for (int pass = 0; pass < 4; ++pass) {
      const int row = pass * 16 + (tid >> 4);
      const int l16 = tid & 15;
      const float* xp = hs + (size_t)sTok[row] * GD + l16 * 4;
      float sm = 0.f, sq = 0.f;
#pragma unroll
      for (int c = 0; c < 12; ++c) {
        float4 u = *(const float4*)(xp + c * 64);
        sm += u.x + u.y + u.z + u.w;
        sq += u.x*u.x + u.y*u.y + u.z*u.z + u.w*u.w;
      }
#pragma unroll
      for (int d = 1; d < 16; d <<= 1) { sm += __shfl_xor(sm, d); sq += __shfl_xor(sq, d); }
      if (l16 == 0) {
        const float mu = sm * (1.f / 768.f);
        sMu[row] = mu;
        sRstd[row] = rsqrtf(sq * (1.f / 768.f) - mu * mu + 1e-5f);
      }
    }
    bar_lds();   // sMu/sRstd/sGam/sBet visible; vmem prefetch NOT drained

    const float muA = sMu[r0],      rsA = sRstd[r0];
    const float muB = sMu[r0 + 32], rsB = sRstd[r0 + 32];

#define XFORM_WRITE(PAR, AA, BB, K0) do {                                       \
    const float4 gv = *(const float4*)&sGam[(K0) + klo];                        \
    const float4 bv = *(const float4*)&sBet[(K0) + klo];                        \
    uint2 oa, ob;                                                               \
    oa.x = (u32)f2bf((AA.x - muA) * rsA * gv.x + bv.x)                          \
         | ((u32)f2bf((AA.y - muA) * rsA * gv.y + bv.y) << 16);                 \
    oa.y = (u32)f2bf((AA.z - muA) * rsA * gv.z + bv.z)                          \
         | ((u32)f2bf((AA.w - muA) * rsA * gv.w + bv.w) << 16);                 \
    ob.x = (u32)f2bf((BB.x - muB) * rsB * gv.x + bv.x)                          \
         | ((u32)f2bf((BB.y - muB) * rsB * gv.y + bv.y) << 16);                 \
    ob.y = (u32)f2bf((BB.z - muB) * rsB * gv.z + bv.z)                          \
         | ((u32)f2bf((BB.w - muB) * rsB * gv.w + bv.w) << 16);                 \
    *(uint2*)&uni.s.A[PAR][kgrp * 512 + r0 * 8 + kin] = oa;                     \
    *(uint2*)&uni.s.A[PAR][kgrp * 512 + (r0 + 32) * 8 + kin] = ob;              \
  } while (0)

    XFORM_WRITE(0, pAa[0], pAb[0], 0);   // waits A(0) regs -> drains B(0) too
    bar_lds();                           // buf0 ready

    // ---- GEMM1: 24 k-steps, 3-buffer, counted vmcnt ----
    f32x4 acc1[4][4];
#pragma unroll
    for (int f = 0; f < 4; ++f)
#pragma unroll
      for (int g = 0; g < 4; ++g) acc1[f][g] = vzero;

#pragma unroll
    for (int kt = 0; kt < 24; ++kt) {
      const int par = kt % 3;
      Frag fa[4], fb[4];
#pragma unroll
      for (int f = 0; f < 4; ++f)
        fa[f].u = *(const uint4*)&uni.s.A[par][quad * 512 + (f * 16 + l15) * 8];
#pragma unroll
      for (int g = 0; g < 4; ++g)
        fb[g].u = *(const uint4*)&uni.s.B[par][quad * 2048 + (wv * 64 + g * 16 + l15) * 8];
      if (kt + 2 < 24) {
        ISSUE_B((kt + 2) % 3, kt + 2);
        __builtin_amdgcn_sched_barrier(0);
        pAa[kt & 1] = *(const float4*)(xA + (kt + 2) * 32);
        pAb[kt & 1] = *(const float4*)(xB + (kt + 2) * 32);
      }
#pragma unroll
      for (int f = 0; f < 4; ++f)
#pragma unroll
        for (int g = 0; g < 4; ++g)
          acc1[f][g] = __builtin_amdgcn_mfma_f32_16x16x32_bf16(fa[f].b, fb[g].b, acc1[f][g], 0, 0, 0);
      if (kt + 1 < 24)
        XFORM_WRITE((kt + 1) % 3, pAa[(kt + 1) & 1], pAb[(kt + 1) & 1], (kt + 1) * 32);
      if (kt < 22) {
        // steady state: 6 ops issued this iter -> vmcnt(6) proves B(kt+1) landed
        asm volatile("s_waitcnt vmcnt(6)" ::: "memory");
      } else {
        // tail: nothing issued this iter -> B(23) is among the newest; drain all
        asm volatile("s_waitcnt vmcnt(0)" ::: "memory");
      }
      __builtin_amdgcn_sched_barrier(0);
      bar_lds();
    }
    bar_lds();   // staging fully read -> uni.h writable

    // GEMM2 B -> registers (pre-tiled w2t; consumed reg-direct, no barriers)
    Frag bW2[8][2];
#pragma unroll
    for (int kt = 0; kt < 8; ++kt)
#pragma unroll
      for (int g = 0; g < 2; ++g)
        bW2[kt][g].u = *(const uint4*)(w2e + kt * 4096 + quad * 1024 +
                                       (size_t)(wv * 32 + g * 16 + l15) * 8);

    // epilogue 1: +b1, relu -> uni.h (stride 264)
#pragma unroll
    for (int f = 0; f < 4; ++f)
#pragma unroll
      for (int g = 0; g < 4; ++g) {
        const int col = wv * 64 + g * 16 + l15;
        const float bias = sBias1[col];
#pragma unroll
        for (int r = 0; r < 4; ++r) {
          const int row = f * 16 + quad * 4 + r;
          uni.h[row * 264 + col] = f2bf(fmaxf(acc1[f][g][r] + bias, 0.f));
        }
      }
    bar_lds();   // h1 visible (B-reg loads stay in flight)

    // ---- GEMM2: h1[64x256] @ regB -> 64x128; no barriers ----
    f32x4 acc2[4][2];
#pragma unroll
    for (int f = 0; f < 4; ++f)
#pragma unroll
      for (int g = 0; g < 2; ++g) acc2[f][g] = vzero;

#pragma unroll
    for (int kt = 0; kt < 8; ++kt) {
      Frag fa2[4];
#pragma unroll
      for (int f = 0; f < 4; ++f)
        fa2[f].u = *(const uint4*)&uni.h[(f * 16 + l15) * 264 + kt * 32 + quad * 8];
#pragma unroll
      for (int f = 0; f < 4; ++f)
#pragma unroll
        for (int g = 0; g < 2; ++g)
          acc2[f][g] = __builtin_amdgcn_mfma_f32_16x16x32_bf16(fa2[f].b, bW2[kt][g].b, acc2[f][g], 0, 0, 0);
    }
    bar_lds();   // all h1 reads done -> overwrite with h2

    // epilogue 2: +b2, relu -> uni.h as h2 (stride 130)
#pragma unroll
    for (int f = 0; f < 4; ++f)
#pragma unroll
      for (int g = 0; g < 2; ++g) {
        const int col = wv * 32 + g * 16 + l15;
        const float bias = sBias2[col];
#pragma unroll
        for (int r = 0; r < 4; ++r) {
          const int row = f * 16 + quad * 4 + r;
          uni.h[row * 130 + col] = f2bf(fmaxf(acc2[f][g][r] + bias, 0.f));
        }
      }
    bar_lds();

    // ---------- GEMM3 + residual + mask + scatter-store (fp32) ----------
    const int m = tid >> 1, o = tid & 1;
    if (m < nRows) {
      float a = sB3[o];
      const u16* h2row = &uni.h[m * 130];
#pragma unroll 16
      for (int k = 0; k < 128; ++k) a += bf2f(h2row[k]) * sW3[o][k];
      const int t = sTok[m];
      const float mk = mask[t];
      const float bs = base[t * 2 + o];
      outp[t * 2 + o] = (0.7f * a + 0.3f * bs) * mk;
    }
  }
#undef XFORM_WRITE
#undef ISSUE_B
}

extern "C" void kernel_launch(void* const* d_in, const int* in_sizes, int n_in,
                              void* d_out, int out_size, void* d_ws, size_t ws_size,
                              hipStream_t stream) {
  const float* hs   = (const float*)d_in[0];
  const float* base = (const float*)d_in[1];
  const int*   prop = (const int*)d_in[2];
  const float* mask = (const float*)d_in[3];
  const float* lng  = (const float*)d_in[4];
  const float* lnb  = (const float*)d_in[5];
  const float* W1   = (const float*)d_in[6];
  const float* b1   = (const float*)d_in[7];
  const float* W2   = (const float*)d_in[8];
  const float* b2   = (const float*)d_in[9];
  const float* W3   = (const float*)d_in[10];
  const float* b3   = (const float*)d_in[11];

  char* ws = (char*)d_ws;
  u16* w1t  = (u16*)(ws + OFF_W1T);
  u16* w2t  = (u16*)(ws + OFF_W2T);
  int* tok  = (int*)(ws + OFF_TOK);
  int* meta = (int*)(ws + OFF_META);
  int* counts2d  = meta;           // 8192 ints
  int* offsets   = meta + 8192;    // 65 ints
  int* tileHead  = meta + 8320;    // 1024 ints
  int* tileRow   = meta + 9344;    // 1024 ints
  int* nTiles    = meta + 10368;
  int* propFlag  = meta + 10369;
  int* cursors_p = meta + 10432;   // 1024 ints (64 bins, 64B-padded)

  setup_kernel<<<128, 256, 0, stream>>>(prop, mask, (u32*)d_out, counts2d,
                                        cursors_p, propFlag);
  transpose_w1<<<768, 256, 0, stream>>>(W1, w1t);
  transpose_w2<<<64 * 32, 256, 0, stream>>>(W2, w2t);
  scan_kernel<<<1, 256, 0, stream>>>(counts2d, offsets, tileHead, tileRow, nTiles);
  scatter_kernel<<<NTOK / 256, 256, 0, stream>>>(prop, mask, offsets, cursors_p, tok, propFlag);
  adapter_gemm<<<640, 256, 0, stream>>>(hs, w1t, w2t, lng, lnb, b1, b2, W3, b3,
                                        base, mask, tok, offsets, tileHead, tileRow,
                                        nTiles, (float*)d_out);
}